// Round 26
// baseline (34.284 us; speedup 1.0000x reference)
//
#include <hip/hip_runtime.h>
#include <math.h>

// Problem constants (batch=1024, dim_z=32, n_samples=32, agg_size=256)
#define B    1024
#define D    32
#define AGG  256
#define NC   4
#define M    8192            // samples per chunk
#define NEV  1024            // eval blocks: 262144 threads x 4 terms

// Table: L(z)=log2 S(z), h*L'(z) on z in [-32,32], h=1/8, 512 float2 nodes/(c,k).
#define TN     512
#define ZMIN   (-32.0f)
#define INVH   8.0f
#define HH     0.125f
#define ZCLAMP 31.8f

// ws: @0 uint counter | @256 float partial[1024] 4KB | @8192 table float2[128*512] 512KB
#define WS_TABLE 8192
#define WS_NEED  (8192 + 128 * TN * 8)

#define LOG2E 1.4426950408889634f
#define LN2   0.6931471805599453f

// ktable2: r23 VERBATIM (measured class ~2.2us) + counter zero at entry.
__global__ __launch_bounds__(1024) void ktable2(const float* __restrict__ mean,
                                                const float* __restrict__ logvar,
                                                float2* __restrict__ table,
                                                unsigned* __restrict__ counter)
{
    const int ck   = blockIdx.x;
    const int t    = threadIdx.x;
    const int lane = t & 63;
    const int wv   = t >> 6;
    if (ck == 0 && t == 0) counter[0] = 0u;    // keval2's last-block counter

    __shared__ float4 ps[AGG];                 // {A, B, C, rho}
    if (t < AGG) {
        const int c   = ck >> 5;
        const int k   = ck & (D - 1);
        const int row = (c << 8) + t;
        const float mu = mean[row * D + k];
        const float lv = logvar[row * D + k];
        const float ev = __builtin_amdgcn_exp2f(-lv * LOG2E);
        const float A  = -0.5f * LOG2E * ev;
        ps[t] = make_float4(A, LOG2E * mu * ev,
                            -0.5f * LOG2E * fmaf(mu * mu, ev, lv),
                            __builtin_amdgcn_exp2f(A * (2.f * HH * HH)));
    }
    __syncthreads();

    const int g0   = lane << 3;
    const float z0 = fmaf((float)g0, HH, ZMIN);
    const float tz = z0 + z0 + HH;
    float a0 = 0.f, a1 = 0.f, a2 = 0.f, a3 = 0.f;
    float a4 = 0.f, a5 = 0.f, a6 = 0.f, a7 = 0.f;
    float d0 = 0.f, d1 = 0.f, d2 = 0.f, d3 = 0.f;
    float d4 = 0.f, d5 = 0.f, d6 = 0.f, d7 = 0.f;
#pragma unroll
    for (int i = 0; i < 16; ++i) {
        const float4 p = ps[(wv << 4) + i];    // wave-uniform LDS broadcast
        const float ap = fmaf(p.x, z0, p.y);
        float w = __builtin_amdgcn_exp2f(fmaf(ap, z0, p.z));
        float dd = HH * fmaf(p.x, tz, p.y);
        dd = fminf(dd, 126.f);                 // anti-NaN (0*inf) guard
        float r = __builtin_amdgcn_exp2f(dd);
        const float qd = p.x * (2.f * HH);
        float q = fmaf(p.x, z0, ap);
        a0 += w; d0 = fmaf(w, q, d0); q += qd;
        w *= r; a1 += w; d1 = fmaf(w, q, d1); q += qd; r *= p.w;
        w *= r; a2 += w; d2 = fmaf(w, q, d2); q += qd; r *= p.w;
        w *= r; a3 += w; d3 = fmaf(w, q, d3); q += qd; r *= p.w;
        w *= r; a4 += w; d4 = fmaf(w, q, d4); q += qd; r *= p.w;
        w *= r; a5 += w; d5 = fmaf(w, q, d5); q += qd; r *= p.w;
        w *= r; a6 += w; d6 = fmaf(w, q, d6); q += qd; r *= p.w;
        w *= r; a7 += w; d7 = fmaf(w, q, d7);
    }

    __shared__ float2 part[16][TN];            // 64KB
    {
        float2* pb = &part[wv][g0];
        pb[0] = make_float2(a0, d0); pb[1] = make_float2(a1, d1);
        pb[2] = make_float2(a2, d2); pb[3] = make_float2(a3, d3);
        pb[4] = make_float2(a4, d4); pb[5] = make_float2(a5, d5);
        pb[6] = make_float2(a6, d6); pb[7] = make_float2(a7, d7);
    }
    __syncthreads();
    if (t < TN) {
        float s = 0.f, d = 0.f;
#pragma unroll
        for (int w = 0; w < 16; ++w) {         // fixed order: deterministic
            const float2 pw = part[w][t];
            s += pw.x; d += pw.y;
        }
        const float sg = fmaxf(s, 1e-30f);
        table[(ck << 9) | t] =
            make_float2(__builtin_amdgcn_logf(sg),
                        d * __builtin_amdgcn_rcpf(sg) * HH);   // {L, h L'}
    }
}

// keval2: r23 body VERBATIM (NEV=1024, native layout, global table — 4 blocks/CU)
// + FUSED FINISH via the fence-free atomic protocol verified in r25:
// relaxed agent atomic store of partial, acq_rel counter, last block reads
// partials with relaxed agent atomic loads (device coherence point),
// fixed-order double tree -> deterministic. No __threadfence anywhere.
__global__ __launch_bounds__(256) void keval2(const float* __restrict__ eps,
                                              const float* __restrict__ mean,
                                              const float* __restrict__ logvar,
                                              const float2* __restrict__ table,
                                              float* __restrict__ partial,
                                              unsigned* __restrict__ counter,
                                              float* __restrict__ out)
{
    const int t    = threadIdx.x;
    const int gidx = (blockIdx.x * 256 + t) << 2;   // flat (c,j,k), k fastest
    const int c    = gidx >> 18;
    const int r18  = gidx & 262143;
    const int j    = r18 >> 5;
    const int k0   = r18 & 31;
    const int row  = (c << 8) + (j >> 5);
    const int ckb  = (c << 5) + k0;

    const float4 e4 = *(const float4*)(eps + gidx);
    const float4 m4 = *(const float4*)(mean + row * D + k0);
    const float4 l4 = *(const float4*)(logvar + row * D + k0);
    const float e[4]  = {e4.x, e4.y, e4.z, e4.w};
    const float mu[4] = {m4.x, m4.y, m4.z, m4.w};
    const float lv[4] = {l4.x, l4.y, l4.z, l4.w};

    float r = 0.f;
#pragma unroll
    for (int kk = 0; kk < 4; ++kk) {
        const float sd = __builtin_amdgcn_exp2f(0.5f * LOG2E * lv[kk]);
        const float z  = fmaf(e[kk], sd, mu[kk]);
        const float zc = fminf(fmaxf(z, -ZCLAMP), ZCLAMP);
        const float x  = fmaf(zc, INVH, 256.0f);    // (zc-ZMIN)*INVH
        const float fg = floorf(x);
        const float f  = x - fg;
        const int  ig  = (int)fg;                   // in [1,510]
        const float2* __restrict__ tg = table + ((ckb + kk) << 9);
        const float2 n0 = tg[ig];                   // aligned 8B
        const float2 n1 = tg[ig + 1];               // aligned 8B
        const float dl  = n1.x - n0.x;
        const float c2  = 3.f * dl - 2.f * n0.y - n1.y;
        const float c3  = n0.y + n1.y - 2.f * dl;
        const float L   = fmaf(f, fmaf(f, fmaf(f, c3, c2), n0.y), n0.x);
        r += fmaf(LN2, L, 0.5f * z * z);
    }

    // deterministic block reduction
    for (int off = 32; off > 0; off >>= 1) r += __shfl_down(r, off, 64);
    __shared__ float wsum[4];
    if ((t & 63) == 0) wsum[t >> 6] = r;
    __syncthreads();

    __shared__ int isLast;
    if (t == 0) {
        const float v = (wsum[0] + wsum[1]) + (wsum[2] + wsum[3]);
        __hip_atomic_store(&partial[blockIdx.x], v, __ATOMIC_RELAXED,
                           __HIP_MEMORY_SCOPE_AGENT);
        const unsigned old = __hip_atomic_fetch_add(counter, 1u, __ATOMIC_ACQ_REL,
                                                    __HIP_MEMORY_SCOPE_AGENT);
        isLast = (old == (unsigned)(NEV - 1));
    }
    __syncthreads();
    if (isLast) {
        double s = 0.0;
#pragma unroll
        for (int i = 0; i < NEV / 256; ++i)         // fixed order: deterministic
            s += (double)__hip_atomic_load(&partial[i * 256 + t], __ATOMIC_RELAXED,
                                           __HIP_MEMORY_SCOPE_AGENT);
        __shared__ double sd2[256];
        sd2[t] = s;
        __syncthreads();
        for (int off = 128; off > 0; off >>= 1) {
            if (t < off) sd2[t] += sd2[t + off];
            __syncthreads();
        }
        if (t == 0)
            out[0] = (float)(sd2[0] * (1.0 / (double)(NC * M))
                             - (double)D * 5.545177444479562);   // - D*ln(256)
    }
}

// ---- fallback (ws too small; not expected) ----
__global__ __launch_bounds__(256) void kfb(const float* __restrict__ eps,
                                           const float* __restrict__ mean,
                                           const float* __restrict__ logvar,
                                           float* __restrict__ partial)
{
    const int bid = blockIdx.x;
    const int ck  = bid >> 3;
    const int q   = bid & 7;
    const int c   = ck >> 5;
    const int k   = ck & (D - 1);
    const int j0  = q << 10;
    const int t   = threadIdx.x;

    __shared__ float4 prm[AGG];
    {
        const int row  = (c << 8) + t;
        const float mu = mean[row * D + k];
        const float lv = logvar[row * D + k];
        const float ev = __builtin_amdgcn_exp2f(-lv * LOG2E);
        prm[t] = make_float4(-0.5f * LOG2E * ev, LOG2E * mu * ev,
                             -0.5f * LOG2E * fmaf(mu * mu, ev, lv),
                             __builtin_amdgcn_exp2f(0.5f * LOG2E * lv));
    }
    __syncthreads();

    float zv[4], acc[4];
#pragma unroll
    for (int u = 0; u < 4; ++u) {
        const int j    = j0 + t + (u << 8);
        const float4 p = prm[j >> 5];
        const float mu = -0.5f * p.y * __builtin_amdgcn_rcpf(p.x);
        zv[u]  = fmaf(eps[(size_t)((c << 13) + j) * D + k], p.w, mu);
        acc[u] = 0.f;
    }
#pragma unroll 4
    for (int i = 0; i < AGG; ++i) {
        const float4 p = prm[i];
#pragma unroll
        for (int u = 0; u < 4; ++u)
            acc[u] += __builtin_amdgcn_exp2f(fmaf(fmaf(p.x, zv[u], p.y), zv[u], p.z));
    }
    float r = 0.f;
#pragma unroll
    for (int u = 0; u < 4; ++u)
        r += LN2 * __builtin_amdgcn_logf(acc[u]) + 0.5f * zv[u] * zv[u];

    for (int off = 32; off > 0; off >>= 1) r += __shfl_down(r, off, 64);
    __shared__ float wsum[4];
    if ((t & 63) == 0) wsum[t >> 6] = r;
    __syncthreads();
    if (t == 0) partial[bid] = (wsum[0] + wsum[1]) + (wsum[2] + wsum[3]);
}

__global__ __launch_bounds__(256) void kfinal_fb(const float* __restrict__ partial,
                                                 float* __restrict__ out)
{
    const int t = threadIdx.x;
    double s = 0.0;
#pragma unroll
    for (int i = 0; i < NEV / 256; ++i) s += (double)partial[i * 256 + t];
    __shared__ double sd[256];
    sd[t] = s;
    __syncthreads();
    for (int off = 128; off > 0; off >>= 1) {
        if (t < off) sd[t] += sd[t + off];
        __syncthreads();
    }
    if (t == 0)
        out[0] = (float)(sd[0] * (1.0 / (double)(NC * M))
                         - (double)D * 5.545177444479562);
}

extern "C" void kernel_launch(void* const* d_in, const int* in_sizes, int n_in,
                              void* d_out, int out_size, void* d_ws, size_t ws_size,
                              hipStream_t stream)
{
    const float* mean   = (const float*)d_in[0];
    const float* logvar = (const float*)d_in[1];
    const float* eps    = (const float*)d_in[2];
    float* out = (float*)d_out;

    unsigned* counter = (unsigned*)d_ws;
    float*    partial = (float*)((char*)d_ws + 256);
    float2*   table   = (float2*)((char*)d_ws + WS_TABLE);

    if (ws_size >= (size_t)WS_NEED) {
        ktable2<<<128, 1024, 0, stream>>>(mean, logvar, table, counter);
        keval2<<<NEV, 256, 0, stream>>>(eps, mean, logvar, table,
                                        partial, counter, out);
    } else {
        kfb<<<NEV, 256, 0, stream>>>(eps, mean, logvar, partial);
        kfinal_fb<<<1, 256, 0, stream>>>(partial, out);
    }
}

// Round 27
// 17.282 us; speedup vs baseline: 1.9838x; 1.9838x over previous
//
#include <hip/hip_runtime.h>
#include <math.h>

// Problem constants (batch=1024, dim_z=32, n_samples=32, agg_size=256)
#define B    1024
#define D    32
#define AGG  256
#define NC   4
#define M    8192            // samples per chunk
#define NEV  1024            // eval blocks: 262144 threads x 4 terms

// Table: L(z)=log2 S(z), h*L'(z) on z in [-32,32], h=1/8, 512 float2 nodes/(c,k).
#define TN     512
#define ZMIN   (-32.0f)
#define INVH   8.0f
#define HH     0.125f
#define ZCLAMP 31.8f

// ws: @0 partial[1024] 4KB | @8192 table float2[128*512] 512KB
#define WS_TABLE 8192
#define WS_NEED  (8192 + 128 * TN * 8)

#define LOG2E 1.4426950408889634f
#define LN2   0.6931471805599453f

// ktable2: fused params + table build (measured ~2.2us; VALUBusy 88% at x24).
// 128 blocks x 1024 threads, block = ck. Threads 0..255 build params (strided
// gather); 16 waves x 16-comp groups x 64 node-threads; thread = 8 consecutive
// nodes via ratio recurrence (w*=r, r*=rho) for S, q=2Az+B walk for S'.
__global__ __launch_bounds__(1024) void ktable2(const float* __restrict__ mean,
                                                const float* __restrict__ logvar,
                                                float2* __restrict__ table)
{
    const int ck   = blockIdx.x;
    const int t    = threadIdx.x;
    const int lane = t & 63;
    const int wv   = t >> 6;

    __shared__ float4 ps[AGG];                 // {A, B, C, rho}
    if (t < AGG) {
        const int c   = ck >> 5;
        const int k   = ck & (D - 1);
        const int row = (c << 8) + t;
        const float mu = mean[row * D + k];
        const float lv = logvar[row * D + k];
        const float ev = __builtin_amdgcn_exp2f(-lv * LOG2E);
        const float A  = -0.5f * LOG2E * ev;
        ps[t] = make_float4(A, LOG2E * mu * ev,
                            -0.5f * LOG2E * fmaf(mu * mu, ev, lv),
                            __builtin_amdgcn_exp2f(A * (2.f * HH * HH)));
    }
    __syncthreads();

    const int g0   = lane << 3;
    const float z0 = fmaf((float)g0, HH, ZMIN);
    const float tz = z0 + z0 + HH;
    float a0 = 0.f, a1 = 0.f, a2 = 0.f, a3 = 0.f;
    float a4 = 0.f, a5 = 0.f, a6 = 0.f, a7 = 0.f;
    float d0 = 0.f, d1 = 0.f, d2 = 0.f, d3 = 0.f;
    float d4 = 0.f, d5 = 0.f, d6 = 0.f, d7 = 0.f;
#pragma unroll
    for (int i = 0; i < 16; ++i) {
        const float4 p = ps[(wv << 4) + i];    // wave-uniform LDS broadcast
        const float ap = fmaf(p.x, z0, p.y);
        float w = __builtin_amdgcn_exp2f(fmaf(ap, z0, p.z));
        float dd = HH * fmaf(p.x, tz, p.y);
        dd = fminf(dd, 126.f);                 // anti-NaN (0*inf) guard
        float r = __builtin_amdgcn_exp2f(dd);
        const float qd = p.x * (2.f * HH);
        float q = fmaf(p.x, z0, ap);
        a0 += w; d0 = fmaf(w, q, d0); q += qd;
        w *= r; a1 += w; d1 = fmaf(w, q, d1); q += qd; r *= p.w;
        w *= r; a2 += w; d2 = fmaf(w, q, d2); q += qd; r *= p.w;
        w *= r; a3 += w; d3 = fmaf(w, q, d3); q += qd; r *= p.w;
        w *= r; a4 += w; d4 = fmaf(w, q, d4); q += qd; r *= p.w;
        w *= r; a5 += w; d5 = fmaf(w, q, d5); q += qd; r *= p.w;
        w *= r; a6 += w; d6 = fmaf(w, q, d6); q += qd; r *= p.w;
        w *= r; a7 += w; d7 = fmaf(w, q, d7);
    }

    __shared__ float2 part[16][TN];            // 64KB
    {
        float2* pb = &part[wv][g0];
        pb[0] = make_float2(a0, d0); pb[1] = make_float2(a1, d1);
        pb[2] = make_float2(a2, d2); pb[3] = make_float2(a3, d3);
        pb[4] = make_float2(a4, d4); pb[5] = make_float2(a5, d5);
        pb[6] = make_float2(a6, d6); pb[7] = make_float2(a7, d7);
    }
    __syncthreads();
    if (t < TN) {
        float s = 0.f, d = 0.f;
#pragma unroll
        for (int w = 0; w < 16; ++w) {         // fixed order: deterministic
            const float2 pw = part[w][t];
            s += pw.x; d += pw.y;
        }
        const float sg = fmaxf(s, 1e-30f);
        table[(ck << 9) | t] =
            make_float2(__builtin_amdgcn_logf(sg),
                        d * __builtin_amdgcn_rcpf(sg) * HH);   // {L, h L'}
    }
}

// keval2: native layout — thread owns 4 consecutive k of one sample j.
// eps/mean/logvar reads coalesced (16B); sd inline; Hermite from GLOBAL table
// (two aligned 8B loads per term; 512KB total -> L2-hot). No LDS, no fences.
__global__ __launch_bounds__(256) void keval2(const float* __restrict__ eps,
                                              const float* __restrict__ mean,
                                              const float* __restrict__ logvar,
                                              const float2* __restrict__ table,
                                              float* __restrict__ partial)
{
    const int t    = threadIdx.x;
    const int gidx = (blockIdx.x * 256 + t) << 2;   // flat (c,j,k), k fastest
    const int c    = gidx >> 18;
    const int r18  = gidx & 262143;
    const int j    = r18 >> 5;
    const int k0   = r18 & 31;
    const int row  = (c << 8) + (j >> 5);
    const int ckb  = (c << 5) + k0;

    const float4 e4 = *(const float4*)(eps + gidx);
    const float4 m4 = *(const float4*)(mean + row * D + k0);
    const float4 l4 = *(const float4*)(logvar + row * D + k0);
    const float e[4]  = {e4.x, e4.y, e4.z, e4.w};
    const float mu[4] = {m4.x, m4.y, m4.z, m4.w};
    const float lv[4] = {l4.x, l4.y, l4.z, l4.w};

    float r = 0.f;
#pragma unroll
    for (int kk = 0; kk < 4; ++kk) {
        const float sd = __builtin_amdgcn_exp2f(0.5f * LOG2E * lv[kk]);
        const float z  = fmaf(e[kk], sd, mu[kk]);
        const float zc = fminf(fmaxf(z, -ZCLAMP), ZCLAMP);
        const float x  = fmaf(zc, INVH, 256.0f);    // (zc-ZMIN)*INVH
        const float fg = floorf(x);
        const float f  = x - fg;
        const int  ig  = (int)fg;                   // in [1,510]
        const float2* __restrict__ tg = table + ((ckb + kk) << 9);
        const float2 n0 = tg[ig];                   // aligned 8B
        const float2 n1 = tg[ig + 1];               // aligned 8B
        const float dl  = n1.x - n0.x;
        const float c2  = 3.f * dl - 2.f * n0.y - n1.y;
        const float c3  = n0.y + n1.y - 2.f * dl;
        const float L   = fmaf(f, fmaf(f, fmaf(f, c3, c2), n0.y), n0.x);
        r += fmaf(LN2, L, 0.5f * z * z);
    }

    for (int off = 32; off > 0; off >>= 1) r += __shfl_down(r, off, 64);
    __shared__ float wsum[4];
    if ((t & 63) == 0) wsum[t >> 6] = r;
    __syncthreads();
    if (t == 0) partial[blockIdx.x] = (wsum[0] + wsum[1]) + (wsum[2] + wsum[3]);
}

// Separate 1-block finish (kernel boundary = coherence; no fences anywhere).
__global__ __launch_bounds__(256) void kfinal(const float* __restrict__ partial,
                                              float* __restrict__ out)
{
    const int t = threadIdx.x;
    double s = 0.0;
#pragma unroll
    for (int i = 0; i < NEV / 256; ++i) s += (double)partial[i * 256 + t];
    __shared__ double sd[256];
    sd[t] = s;
    __syncthreads();
    for (int off = 128; off > 0; off >>= 1) {
        if (t < off) sd[t] += sd[t + off];
        __syncthreads();
    }
    if (t == 0)
        out[0] = (float)(sd[0] * (1.0 / (double)(NC * M))
                         - (double)D * 5.545177444479562);   // - D*ln(256)
}

// ---- fallback (ws too small; not expected) ----
__global__ __launch_bounds__(256) void kfb(const float* __restrict__ eps,
                                           const float* __restrict__ mean,
                                           const float* __restrict__ logvar,
                                           float* __restrict__ partial)
{
    const int bid = blockIdx.x;
    const int ck  = bid >> 3;
    const int q   = bid & 7;
    const int c   = ck >> 5;
    const int k   = ck & (D - 1);
    const int j0  = q << 10;
    const int t   = threadIdx.x;

    __shared__ float4 prm[AGG];
    {
        const int row  = (c << 8) + t;
        const float mu = mean[row * D + k];
        const float lv = logvar[row * D + k];
        const float ev = __builtin_amdgcn_exp2f(-lv * LOG2E);
        prm[t] = make_float4(-0.5f * LOG2E * ev, LOG2E * mu * ev,
                             -0.5f * LOG2E * fmaf(mu * mu, ev, lv),
                             __builtin_amdgcn_exp2f(0.5f * LOG2E * lv));
    }
    __syncthreads();

    float zv[4], acc[4];
#pragma unroll
    for (int u = 0; u < 4; ++u) {
        const int j    = j0 + t + (u << 8);
        const float4 p = prm[j >> 5];
        const float mu = -0.5f * p.y * __builtin_amdgcn_rcpf(p.x);
        zv[u]  = fmaf(eps[(size_t)((c << 13) + j) * D + k], p.w, mu);
        acc[u] = 0.f;
    }
#pragma unroll 4
    for (int i = 0; i < AGG; ++i) {
        const float4 p = prm[i];
#pragma unroll
        for (int u = 0; u < 4; ++u)
            acc[u] += __builtin_amdgcn_exp2f(fmaf(fmaf(p.x, zv[u], p.y), zv[u], p.z));
    }
    float r = 0.f;
#pragma unroll
    for (int u = 0; u < 4; ++u)
        r += LN2 * __builtin_amdgcn_logf(acc[u]) + 0.5f * zv[u] * zv[u];

    for (int off = 32; off > 0; off >>= 1) r += __shfl_down(r, off, 64);
    __shared__ float wsum[4];
    if ((t & 63) == 0) wsum[t >> 6] = r;
    __syncthreads();
    if (t == 0) partial[bid] = (wsum[0] + wsum[1]) + (wsum[2] + wsum[3]);
}

extern "C" void kernel_launch(void* const* d_in, const int* in_sizes, int n_in,
                              void* d_out, int out_size, void* d_ws, size_t ws_size,
                              hipStream_t stream)
{
    const float* mean   = (const float*)d_in[0];
    const float* logvar = (const float*)d_in[1];
    const float* eps    = (const float*)d_in[2];
    float* out = (float*)d_out;

    float*  partial = (float*)d_ws;
    float2* table   = (float2*)((char*)d_ws + WS_TABLE);

    if (ws_size >= (size_t)WS_NEED) {
        ktable2<<<128, 1024, 0, stream>>>(mean, logvar, table);
        keval2<<<NEV, 256, 0, stream>>>(eps, mean, logvar, table, partial);
    } else {
        kfb<<<NEV, 256, 0, stream>>>(eps, mean, logvar, partial);
    }
    kfinal<<<1, 256, 0, stream>>>(partial, out);
}